// Round 1
// baseline (9.712 us; speedup 1.0000x reference)
//
#include <hip/hip_runtime.h>

#define N_QUBITS 12

// out[s][k] = prod_{j<=k} cos(x[s][j])
// Derivation: RZ is diagonal -> |amp|^2 unchanged -> weights irrelevant.
// CNOT chain maps bits b -> prefix-XOR c_k = b_0^...^b_k. Bits independent
// after RX with E[(-1)^{b_j}] = cos(x_j) => <Z_k> = prod_{j<=k} cos(x_j).
__global__ void qlayer_prefix_cos(const float* __restrict__ x,
                                  float* __restrict__ out,
                                  int n_samples) {
    int s = blockIdx.x * blockDim.x + threadIdx.x;
    if (s >= n_samples) return;

    const float4* xv = reinterpret_cast<const float4*>(x + (size_t)s * N_QUBITS);
    float4 a = xv[0];
    float4 b = xv[1];
    float4 c = xv[2];

    float v[N_QUBITS] = {a.x, a.y, a.z, a.w,
                         b.x, b.y, b.z, b.w,
                         c.x, c.y, c.z, c.w};
    float o[N_QUBITS];
    float p = 1.0f;
#pragma unroll
    for (int j = 0; j < N_QUBITS; ++j) {
        p *= __cosf(v[j]);
        o[j] = p;
    }

    float4* ov = reinterpret_cast<float4*>(out + (size_t)s * N_QUBITS);
    ov[0] = make_float4(o[0], o[1], o[2], o[3]);
    ov[1] = make_float4(o[4], o[5], o[6], o[7]);
    ov[2] = make_float4(o[8], o[9], o[10], o[11]);
}

extern "C" void kernel_launch(void* const* d_in, const int* in_sizes, int n_in,
                              void* d_out, int out_size, void* d_ws, size_t ws_size,
                              hipStream_t stream) {
    const float* x = (const float*)d_in[0];
    // d_in[1] (weights) provably does not affect the output: RZ is diagonal.
    float* out = (float*)d_out;

    int n_samples = out_size / N_QUBITS;  // 16*512 = 8192
    int block = 256;
    int grid = (n_samples + block - 1) / block;
    qlayer_prefix_cos<<<grid, block, 0, stream>>>(x, out, n_samples);
}